// Round 4
// baseline (133.052 us; speedup 1.0000x reference)
//
#include <hip/hip_runtime.h>

// Problem constants (B=4, N=512, D=128, all f32)
#define BB 4
#define NN 512
#define DD 128

static constexpr float LOG2E = 1.4426950408889634f;
#define EXP2F(x) __builtin_amdgcn_exp2f(x)

// ---------------------------------------------------------------------------
// K1: fused projections + per-channel softmax attention.
// grid = 256 blocks = (b, d-pair), 1 block/CU; block = 512 threads.
// Phase 1: thread m computes qp/kp/vp[b,m,d0..d0+1] (6 dots of length 128),
//   weight rows wave-uniform, x rows per-thread float4 (L1/L2 resident).
//   Results -> LDS (qp pre-scaled by log2e, masked rows -> 0).
// Phase 2: thread t = (dd = t>>8, n0 = t&255) handles queries {n0, n0+256}
//   for channel d0+dd: each k/v ds_read_b128 serves 2 queries (halves LDS
//   instr count vs R3). No max-subtraction: |score| <= ~17 in exp2 domain,
//   f32-safe. Masked n: qv=0 -> uniform softmax == reference semantics.
// ---------------------------------------------------------------------------
__global__ __launch_bounds__(512) void fused_attn_kernel(
    const float* __restrict__ q, const float* __restrict__ k,
    const float* __restrict__ v, const int* __restrict__ mask,
    const float* __restrict__ Wq, const float* __restrict__ bq,
    const float* __restrict__ Wk, const float* __restrict__ bk,
    const float* __restrict__ Wv, const float* __restrict__ bv,
    float* __restrict__ att)
{
    __shared__ float sq[2][NN];
    __shared__ float sk[2][NN];
    __shared__ float sv[2][NN];

    const int b  = blockIdx.x >> 6;          // batch
    const int d0 = (blockIdx.x & 63) << 1;   // first channel of the pair
    const int m  = threadIdx.x;              // row this thread projects

    // ---- phase 1: projections for rows m, channels d0, d0+1 ----
    const float4* xq = (const float4*)(q + (b * NN + m) * DD);
    const float4* xk = (const float4*)(k + (b * NN + m) * DD);
    const float4* xv = (const float4*)(v + (b * NN + m) * DD);
    const float4* wq0 = (const float4*)(Wq + (d0    ) * DD);
    const float4* wq1 = (const float4*)(Wq + (d0 + 1) * DD);
    const float4* wk0 = (const float4*)(Wk + (d0    ) * DD);
    const float4* wk1 = (const float4*)(Wk + (d0 + 1) * DD);
    const float4* wv0 = (const float4*)(Wv + (d0    ) * DD);
    const float4* wv1 = (const float4*)(Wv + (d0 + 1) * DD);

    float aq0 = 0.f, aq1 = 0.f, ak0 = 0.f, ak1 = 0.f, av0 = 0.f, av1 = 0.f;
    #pragma unroll 4
    for (int j4 = 0; j4 < DD / 4; ++j4) {
        const float4 x0 = xq[j4];
        const float4 x1 = xk[j4];
        const float4 x2 = xv[j4];
        const float4 a0 = wq0[j4];  // wave-uniform
        const float4 a1 = wq1[j4];
        const float4 c0 = wk0[j4];
        const float4 c1 = wk1[j4];
        const float4 e0 = wv0[j4];
        const float4 e1 = wv1[j4];
        aq0 = fmaf(x0.x, a0.x, fmaf(x0.y, a0.y, fmaf(x0.z, a0.z, fmaf(x0.w, a0.w, aq0))));
        aq1 = fmaf(x0.x, a1.x, fmaf(x0.y, a1.y, fmaf(x0.z, a1.z, fmaf(x0.w, a1.w, aq1))));
        ak0 = fmaf(x1.x, c0.x, fmaf(x1.y, c0.y, fmaf(x1.z, c0.z, fmaf(x1.w, c0.w, ak0))));
        ak1 = fmaf(x1.x, c1.x, fmaf(x1.y, c1.y, fmaf(x1.z, c1.z, fmaf(x1.w, c1.w, ak1))));
        av0 = fmaf(x2.x, e0.x, fmaf(x2.y, e0.y, fmaf(x2.z, e0.z, fmaf(x2.w, e0.w, av0))));
        av1 = fmaf(x2.x, e1.x, fmaf(x2.y, e1.y, fmaf(x2.z, e1.z, fmaf(x2.w, e1.w, av1))));
    }

    const int mv = mask[b * NN + m];
    sq[0][m] = mv ? (aq0 + bq[d0    ]) * LOG2E : 0.f;
    sq[1][m] = mv ? (aq1 + bq[d0 + 1]) * LOG2E : 0.f;
    sk[0][m] = ak0 + bk[d0    ];
    sk[1][m] = ak1 + bk[d0 + 1];
    sv[0][m] = av0 + bv[d0    ];
    sv[1][m] = av1 + bv[d0 + 1];
    __syncthreads();

    // ---- phase 2: attention, thread = (dd, {n0, n0+256}) ----
    const int dd = threadIdx.x >> 8;     // which channel of the pair
    const int n0 = threadIdx.x & 255;
    const int n1 = n0 + 256;

    const float qv0 = sq[dd][n0];
    const float qv1 = sq[dd][n1];
    const float4* kc = (const float4*)sk[dd];
    const float4* vc = (const float4*)sv[dd];

    float na0 = 0.f, nb0 = 0.f, da0 = 0.f, db0 = 0.f;
    float na1 = 0.f, nb1 = 0.f, da1 = 0.f, db1 = 0.f;
    #pragma unroll 8
    for (int m4 = 0; m4 < NN / 4; ++m4) {
        const float4 k4 = kc[m4];        // one b128 serves 2 queries
        const float4 v4 = vc[m4];
        const float p0 = EXP2F(qv0 * k4.x);
        const float p1 = EXP2F(qv0 * k4.y);
        const float p2 = EXP2F(qv0 * k4.z);
        const float p3 = EXP2F(qv0 * k4.w);
        const float r0 = EXP2F(qv1 * k4.x);
        const float r1 = EXP2F(qv1 * k4.y);
        const float r2 = EXP2F(qv1 * k4.z);
        const float r3 = EXP2F(qv1 * k4.w);
        na0 = fmaf(p0, v4.x, na0); nb0 = fmaf(p1, v4.y, nb0);
        na0 = fmaf(p2, v4.z, na0); nb0 = fmaf(p3, v4.w, nb0);
        na1 = fmaf(r0, v4.x, na1); nb1 = fmaf(r1, v4.y, nb1);
        na1 = fmaf(r2, v4.z, na1); nb1 = fmaf(r3, v4.w, nb1);
        da0 += p0 + p2; db0 += p1 + p3;
        da1 += r0 + r2; db1 += r1 + r3;
    }

    att[(b * NN + n0) * DD + d0 + dd] = (na0 + nb0) / (da0 + db0);
    att[(b * NN + n1) * DD + d0 + dd] = (na1 + nb1) / (da1 + db1);
}

// ---------------------------------------------------------------------------
// K2: output projection, self-contained (no global weight repack).
// Phase 0: stage Wo into LDS packed as sW4[j4*128+e] = Wo[e][4j4..4j4+3]
//   (coalesced global reads; one-time). Phase 1: lane = e -> ds reads are
//   lane-contiguous (64 consecutive float4s per wave = conflict-free);
//   att rows wave-uniform. out[g,e] = att[g,:]·Wo[e,:] + bo[e].
// grid 512 x 512 thr (4 rows/block); LDS 64 KB -> 2 blocks/CU, 4 waves/SIMD.
// ---------------------------------------------------------------------------
__global__ __launch_bounds__(512) void outproj_kernel(
    const float* __restrict__ att, const float* __restrict__ Wo,
    const float* __restrict__ bo, float* __restrict__ out)
{
    __shared__ float4 sW4[32 * DD];      // 64 KB

    const int tid = threadIdx.x;
    const float4* Wo4 = (const float4*)Wo;
    #pragma unroll
    for (int p = 0; p < 8; ++p) {
        const int f = p * 512 + tid;     // float4 index: e = f>>5, j4 = f&31
        sW4[(f & 31) * DD + (f >> 5)] = Wo4[f];
    }
    __syncthreads();

    const int e = tid & (DD - 1);
    const int g = blockIdx.x * 4 + (tid >> 7);
    const float4* ar = (const float4*)(att + g * DD);

    float acc = 0.f;
    #pragma unroll 8
    for (int j4 = 0; j4 < DD / 4; ++j4) {
        const float4 w = sW4[j4 * DD + e];   // lane-contiguous b128
        const float4 a = ar[j4];             // wave-uniform
        acc = fmaf(a.x, w.x, fmaf(a.y, w.y, fmaf(a.z, w.z, fmaf(a.w, w.w, acc))));
    }

    out[g * DD + e] = acc + bo[e];           // coalesced
}

// ---------------------------------------------------------------------------
extern "C" void kernel_launch(void* const* d_in, const int* in_sizes, int n_in,
                              void* d_out, int out_size, void* d_ws, size_t ws_size,
                              hipStream_t stream)
{
    const float* q    = (const float*)d_in[0];
    const float* k    = (const float*)d_in[1];
    const float* v    = (const float*)d_in[2];
    const int*   mask = (const int*)  d_in[3];
    const float* Wq   = (const float*)d_in[4];
    const float* bq   = (const float*)d_in[5];
    const float* Wk   = (const float*)d_in[6];
    const float* bk   = (const float*)d_in[7];
    const float* Wv   = (const float*)d_in[8];
    const float* bv   = (const float*)d_in[9];
    const float* Wo   = (const float*)d_in[10];
    const float* bo   = (const float*)d_in[11];
    float* out = (float*)d_out;

    float* att = (float*)d_ws;           // [B*N][D], 1 MB

    fused_attn_kernel<<<BB * DD / 2, 512, 0, stream>>>(
        q, k, v, mask, Wq, bq, Wk, bk, Wv, bv, att);

    outproj_kernel<<<BB * NN / 4, 512, 0, stream>>>(att, Wo, bo, out);
}

// Round 5
// 127.082 us; speedup vs baseline: 1.0470x; 1.0470x over previous
//
#include <hip/hip_runtime.h>

// Problem constants (B=4, N=512, D=128, all f32)
#define BB 4
#define NN 512
#define DD 128

static constexpr float LOG2E = 1.4426950408889634f;
#define EXP2F(x) __builtin_amdgcn_exp2f(x)

// ---------------------------------------------------------------------------
// K0: repack all 4 weight matrices into ws.
//   WTp[t][j4][e][c] = W_t[e][j4*4+c]   (t = 0:q 1:k 2:v 3:o, c = 0..3)
// so a proj thread (lane = e) loads one coalesced float4 of 4 consecutive
// j's for its channel e.
// ---------------------------------------------------------------------------
__global__ __launch_bounds__(256) void wtrans_kernel(
    const float* __restrict__ Wq, const float* __restrict__ Wk,
    const float* __restrict__ Wv, const float* __restrict__ Wo,
    float* __restrict__ WTp)
{
    const int l = blockIdx.x * 256 + threadIdx.x;   // 0..65535
    const int t = l >> 14;
    const int e = (l >> 7) & (DD - 1);
    const int j = l & (DD - 1);
    const float* W = (t == 0) ? Wq : (t == 1) ? Wk : (t == 2) ? Wv : Wo;
    WTp[(t << 14) + (j >> 2) * (DD * 4) + e * 4 + (j & 3)] = W[e * DD + j];
}

// ---------------------------------------------------------------------------
// K1: input projections -> transposed columns.
// grid (256,3) x 512 thr = 6144 waves = 6 waves/SIMD.
// lane = channel e; wave-pair sub = tid>>7 owns 2 rows. Weight loads are
// per-lane coalesced dwordx4; x rows wave-uniform -> s_load_dwordx4.
//   qpT[b*D+e][n] = mask ? (q[b,n,:]·Wq[e,:] + bq[e]) * LOG2E : 0
//   kpT/vpT analogous (no mask, scale 1).
// Mask folded here: masked QUERY rows -> qp=0 -> uniform softmax later,
// exactly the reference's -1e9-fill semantics. kp/vp unmasked (correct:
// reference masks by query index n only).
// ---------------------------------------------------------------------------
__global__ __launch_bounds__(512) void proj_kernel(
    const float* __restrict__ q, const float* __restrict__ k,
    const float* __restrict__ v, const float* __restrict__ WTp,
    const float* __restrict__ bq, const float* __restrict__ bk,
    const float* __restrict__ bv, const int* __restrict__ mask,
    float* __restrict__ qpT, float* __restrict__ kpT, float* __restrict__ vpT)
{
    const int t   = blockIdx.y;                  // 0=q, 1=k, 2=v
    const int e   = threadIdx.x & (DD - 1);      // output channel, lane dim
    const int sub = threadIdx.x >> 7;            // uniform per wave-pair
    const int g0  = blockIdx.x * 8 + sub * 2;    // rows g0, g0+1

    const float*  x    = (t == 0) ? q   : (t == 1) ? k   : v;
    const float4* wt4  = (const float4*)(WTp + (t << 14));
    const float*  bias = (t == 0) ? bq  : (t == 1) ? bk  : bv;
    float*        outp = (t == 0) ? qpT : (t == 1) ? kpT : vpT;

    const float4* x0 = (const float4*)(x + g0 * DD);
    const float4* x1 = (const float4*)(x + (g0 + 1) * DD);

    float a0 = 0.f, a1 = 0.f;
    #pragma unroll 8
    for (int j4 = 0; j4 < DD / 4; ++j4) {
        const float4 w  = wt4[j4 * DD + e];      // coalesced dwordx4
        const float4 r0 = x0[j4];                // uniform -> s_load_dwordx4
        const float4 r1 = x1[j4];
        a0 = fmaf(r0.x, w.x, fmaf(r0.y, w.y, fmaf(r0.z, w.z, fmaf(r0.w, w.w, a0))));
        a1 = fmaf(r1.x, w.x, fmaf(r1.y, w.y, fmaf(r1.z, w.z, fmaf(r1.w, w.w, a1))));
    }

    const float be = bias[e];
    #pragma unroll
    for (int r = 0; r < 2; ++r) {
        const int g = g0 + r;
        const int b = g >> 9, n = g & (NN - 1);
        float val = (r == 0 ? a0 : a1) + be;
        if (t == 0) val = (mask[g] != 0) ? val * LOG2E : 0.f;  // mask uniform
        outp[(b * DD + e) * NN + n] = val;
    }
}

// ---------------------------------------------------------------------------
// K2: per-channel softmax attention, register-blocked.
// grid 512 = (b,d), 2 blocks/CU = 16 waves/CU = 4 waves/SIMD.
// Thread (h = tid>>7, i = tid&127): keys [h*128, h*128+128) for queries
// {i, i+128, i+256, i+384}. Each ds_read_b128 pair (k4,v4) feeds 4 queries
// -> LDS pipe ~5.1 us/CU, under the 6.8 us exp floor. Broadcast reads
// (same addr per wave) are conflict-free. Partial num/den combined via LDS.
// No max-subtraction: |score| <= ~17 in exp2 domain, f32-safe.
// ---------------------------------------------------------------------------
__global__ __launch_bounds__(512) void attn_kernel(
    const float* __restrict__ qpT, const float* __restrict__ kpT,
    const float* __restrict__ vpT, float* __restrict__ att)
{
    __shared__ float sk[NN];
    __shared__ float sv[NN];
    __shared__ float pn[4][NN];      // partial numerators per key-quarter
    __shared__ float pd[4][NN];      // partial denominators

    const int bd  = blockIdx.x;      // 0..511
    const int b   = bd >> 7;
    const int d   = bd & (DD - 1);
    const int tid = threadIdx.x;
    const int h   = tid >> 7;        // key quarter, uniform per wave-pair
    const int i   = tid & 127;

    sk[tid] = kpT[bd * NN + tid];    // coalesced
    sv[tid] = vpT[bd * NN + tid];

    float qv[4];
    #pragma unroll
    for (int j = 0; j < 4; ++j)
        qv[j] = qpT[bd * NN + i + j * 128];   // coalesced (4 loads)
    __syncthreads();

    const float4* kc = (const float4*)sk;
    const float4* vc = (const float4*)sv;

    float na[4] = {0.f, 0.f, 0.f, 0.f}, nb[4] = {0.f, 0.f, 0.f, 0.f};
    float da[4] = {0.f, 0.f, 0.f, 0.f}, db[4] = {0.f, 0.f, 0.f, 0.f};

    const int m4lo = h * 32;
    #pragma unroll 4
    for (int m4 = m4lo; m4 < m4lo + 32; ++m4) {
        const float4 k4 = kc[m4];    // broadcast, serves 4 queries
        const float4 v4 = vc[m4];
        #pragma unroll
        for (int j = 0; j < 4; ++j) {
            const float p0 = EXP2F(qv[j] * k4.x);
            const float p1 = EXP2F(qv[j] * k4.y);
            const float p2 = EXP2F(qv[j] * k4.z);
            const float p3 = EXP2F(qv[j] * k4.w);
            na[j] = fmaf(p0, v4.x, na[j]); nb[j] = fmaf(p1, v4.y, nb[j]);
            na[j] = fmaf(p2, v4.z, na[j]); nb[j] = fmaf(p3, v4.w, nb[j]);
            da[j] += p0 + p2;              db[j] += p1 + p3;
        }
    }

    #pragma unroll
    for (int j = 0; j < 4; ++j) {
        pn[h][i + j * 128] = na[j] + nb[j];   // stride-1 across lanes
        pd[h][i + j * 128] = da[j] + db[j];
    }
    __syncthreads();

    // combine: thread tid finalizes query tid
    const float num = pn[0][tid] + pn[1][tid] + pn[2][tid] + pn[3][tid];
    const float den = pd[0][tid] + pd[1][tid] + pd[2][tid] + pd[3][tid];
    att[(b * NN + tid) * DD + d] = num / den;   // 4B scattered, L2-absorbed
}

// ---------------------------------------------------------------------------
// K3: output projection. out[b,n,e] = att[b,n,:]·Wo[e,:] + bo[e]
// grid 512 x 512 thr = 4 waves/SIMD. lane = e, sub = tid>>7 owns 1 row.
// Wo^T loads per-lane coalesced dwordx4 (WTp slot 3); att rows uniform.
// ---------------------------------------------------------------------------
__global__ __launch_bounds__(512) void outproj_kernel(
    const float* __restrict__ att, const float* __restrict__ WTp,
    const float* __restrict__ bo, float* __restrict__ out)
{
    const int e   = threadIdx.x & (DD - 1);
    const int sub = threadIdx.x >> 7;
    const int g   = blockIdx.x * 4 + sub;

    const float4* wt4 = (const float4*)(WTp + (3 << 14));   // Wo slot
    const float4* xr  = (const float4*)(att + g * DD);

    float acc = 0.f;
    #pragma unroll 8
    for (int j4 = 0; j4 < DD / 4; ++j4) {
        const float4 w = wt4[j4 * DD + e];   // coalesced dwordx4
        const float4 a = xr[j4];             // uniform -> s_load_dwordx4
        acc = fmaf(a.x, w.x, fmaf(a.y, w.y, fmaf(a.z, w.z, fmaf(a.w, w.w, acc))));
    }

    out[g * DD + e] = acc + bo[e];           // coalesced
}

// ---------------------------------------------------------------------------
extern "C" void kernel_launch(void* const* d_in, const int* in_sizes, int n_in,
                              void* d_out, int out_size, void* d_ws, size_t ws_size,
                              hipStream_t stream)
{
    const float* q    = (const float*)d_in[0];
    const float* k    = (const float*)d_in[1];
    const float* v    = (const float*)d_in[2];
    const int*   mask = (const int*)  d_in[3];
    const float* Wq   = (const float*)d_in[4];
    const float* bq   = (const float*)d_in[5];
    const float* Wk   = (const float*)d_in[6];
    const float* bk   = (const float*)d_in[7];
    const float* Wv   = (const float*)d_in[8];
    const float* bv   = (const float*)d_in[9];
    const float* Wo   = (const float*)d_in[10];
    const float* bo   = (const float*)d_in[11];
    float* out = (float*)d_out;

    // ws layout (floats): qpT | kpT | vpT | att | WTp[4]  (~4.25 MB)
    float* ws  = (float*)d_ws;
    float* qpT = ws;                           // [B*D][N], masked+log2e-scaled
    float* kpT = ws + 1 * BB * DD * NN;        // [B*D][N]
    float* vpT = ws + 2 * BB * DD * NN;        // [B*D][N]
    float* att = ws + 3 * BB * DD * NN;        // [B*N][D]
    float* WTp = ws + 4 * BB * DD * NN;        // [4][32][128][4] packed weights

    wtrans_kernel<<<4 * DD * DD / 256, 256, 0, stream>>>(Wq, Wk, Wv, Wo, WTp);

    dim3 pgrid(BB * NN / 8, 3);
    proj_kernel<<<pgrid, 512, 0, stream>>>(q, k, v, WTp, bq, bk, bv, mask,
                                           qpT, kpT, vpT);

    attn_kernel<<<BB * DD, 512, 0, stream>>>(qpT, kpT, vpT, att);

    outproj_kernel<<<BB * NN / 4, 512, 0, stream>>>(att, WTp, bo, out);
}

// Round 6
// 126.097 us; speedup vs baseline: 1.0552x; 1.0078x over previous
//
#include <hip/hip_runtime.h>

// Problem constants (B=4, N=512, D=128, all f32)
#define BB 4
#define NN 512
#define DD 128

static constexpr float LOG2E = 1.4426950408889634f;
#define EXP2F(x) __builtin_amdgcn_exp2f(x)

// ---------------------------------------------------------------------------
// K0: repack all 4 weight matrices into ws.
//   WTp[t][j4][e][c] = W_t[e][j4*4+c]   (t = 0:q 1:k 2:v 3:o)
// proj/outproj lane e then loads one coalesced float4 per j4.
// ---------------------------------------------------------------------------
__global__ __launch_bounds__(256) void wtrans_kernel(
    const float* __restrict__ Wq, const float* __restrict__ Wk,
    const float* __restrict__ Wv, const float* __restrict__ Wo,
    float* __restrict__ WTp)
{
    const int l = blockIdx.x * 256 + threadIdx.x;   // 0..65535
    const int t = l >> 14;
    const int e = (l >> 7) & (DD - 1);
    const int j = l & (DD - 1);
    const float* W = (t == 0) ? Wq : (t == 1) ? Wk : (t == 2) ? Wv : Wo;
    WTp[(t << 14) + (j >> 2) * (DD * 4) + e * 4 + (j & 3)] = W[e * DD + j];
}

// ---------------------------------------------------------------------------
// K1: input projections -> transposed columns. 4 rows/thread.
// grid (256,3) x 256 thr = 3 blocks/CU = 12 waves/CU (even).
// lane = channel e; sub = tid>>7 owns rows g0..g0+3. One coalesced weight
// dwordx4 per j4 amortized over 4 rows (halves L2 weight traffic vs R5:
// 196 -> 98 MB aggregate); x rows wave-uniform (broadcast). 16 indep FMA
// chains/thread.
//   qpT[b*D+e][n] = mask ? (q·Wq[e]+bq[e]) * LOG2E : 0 ; kpT/vpT plain.
// ---------------------------------------------------------------------------
__global__ __launch_bounds__(256) void proj_kernel(
    const float* __restrict__ q, const float* __restrict__ k,
    const float* __restrict__ v, const float* __restrict__ WTp,
    const float* __restrict__ bq, const float* __restrict__ bk,
    const float* __restrict__ bv, const int* __restrict__ mask,
    float* __restrict__ qpT, float* __restrict__ kpT, float* __restrict__ vpT)
{
    const int t   = blockIdx.y;                  // 0=q, 1=k, 2=v
    const int e   = threadIdx.x & (DD - 1);      // output channel, lane dim
    const int sub = threadIdx.x >> 7;            // uniform per wave
    const int g0  = blockIdx.x * 8 + sub * 4;    // rows g0..g0+3

    const float*  x    = (t == 0) ? q   : (t == 1) ? k   : v;
    const float4* wt4  = (const float4*)(WTp + (t << 14));
    const float*  bias = (t == 0) ? bq  : (t == 1) ? bk  : bv;
    float*        outp = (t == 0) ? qpT : (t == 1) ? kpT : vpT;

    const float4* x0 = (const float4*)(x + (g0 + 0) * DD);
    const float4* x1 = (const float4*)(x + (g0 + 1) * DD);
    const float4* x2 = (const float4*)(x + (g0 + 2) * DD);
    const float4* x3 = (const float4*)(x + (g0 + 3) * DD);

    float a0 = 0.f, a1 = 0.f, a2 = 0.f, a3 = 0.f;
    #pragma unroll 4
    for (int j4 = 0; j4 < DD / 4; ++j4) {
        const float4 w  = wt4[j4 * DD + e];      // coalesced dwordx4
        const float4 r0 = x0[j4];                // wave-uniform broadcast
        const float4 r1 = x1[j4];
        const float4 r2 = x2[j4];
        const float4 r3 = x3[j4];
        a0 = fmaf(r0.x, w.x, fmaf(r0.y, w.y, fmaf(r0.z, w.z, fmaf(r0.w, w.w, a0))));
        a1 = fmaf(r1.x, w.x, fmaf(r1.y, w.y, fmaf(r1.z, w.z, fmaf(r1.w, w.w, a1))));
        a2 = fmaf(r2.x, w.x, fmaf(r2.y, w.y, fmaf(r2.z, w.z, fmaf(r2.w, w.w, a2))));
        a3 = fmaf(r3.x, w.x, fmaf(r3.y, w.y, fmaf(r3.z, w.z, fmaf(r3.w, w.w, a3))));
    }

    const float be = bias[e];
    float acc[4] = {a0, a1, a2, a3};
    #pragma unroll
    for (int r = 0; r < 4; ++r) {
        const int g = g0 + r;
        const int b = g >> 9, n = g & (NN - 1);
        float val = acc[r] + be;
        if (t == 0) val = (mask[g] != 0) ? val * LOG2E : 0.f;  // uniform branch
        outp[(b * DD + e) * NN + n] = val;
    }
}

// ---------------------------------------------------------------------------
// K2: per-channel softmax attention, 8 queries x 64 keys per thread.
// grid 512 = (b,d) x 512 thr = 2 blocks/CU = 4 waves/SIMD.
// Thread (h = tid>>6, i = tid&63): keys [h*64, h*64+64) for queries
// {i + j*64}. Each ds_read_b128 pair feeds 8 queries (32 indep exps of
// ILP per pair; ds-pipe ~2.6 us/CU, exp floor 6.8 us). All LDS access
// stride-1 across lanes (conflict-free). Partials combined via LDS.
// No max-subtraction: scores bounded in exp2 domain, f32-safe (validated
// absmax 4.9e-4 across R1-R5).
// ---------------------------------------------------------------------------
__global__ __launch_bounds__(512) void attn_kernel(
    const float* __restrict__ qpT, const float* __restrict__ kpT,
    const float* __restrict__ vpT, float* __restrict__ att)
{
    __shared__ float sk[NN];
    __shared__ float sv[NN];
    __shared__ float pn[8][NN];      // partial numerators per key-eighth
    __shared__ float pd[8][NN];      // partial denominators

    const int bd  = blockIdx.x;      // 0..511
    const int b   = bd >> 7;
    const int d   = bd & (DD - 1);
    const int tid = threadIdx.x;
    const int h   = tid >> 6;        // key eighth, uniform per wave
    const int i   = tid & 63;

    sk[tid] = kpT[bd * NN + tid];    // coalesced
    sv[tid] = vpT[bd * NN + tid];

    float qv[8];
    #pragma unroll
    for (int j = 0; j < 8; ++j)
        qv[j] = qpT[bd * NN + i + j * 64];   // coalesced 64-wide
    __syncthreads();

    const float4* kc = (const float4*)sk;
    const float4* vc = (const float4*)sv;

    float na[8], da[8];
    #pragma unroll
    for (int j = 0; j < 8; ++j) { na[j] = 0.f; da[j] = 0.f; }

    const int m4lo = h * 16;
    #pragma unroll 2
    for (int m4 = m4lo; m4 < m4lo + 16; ++m4) {
        const float4 k4 = kc[m4];    // broadcast, serves 8 queries
        const float4 v4 = vc[m4];
        #pragma unroll
        for (int j = 0; j < 8; ++j) {
            const float p0 = EXP2F(qv[j] * k4.x);
            const float p1 = EXP2F(qv[j] * k4.y);
            const float p2 = EXP2F(qv[j] * k4.z);
            const float p3 = EXP2F(qv[j] * k4.w);
            na[j] = fmaf(p0, v4.x, na[j]);
            na[j] = fmaf(p1, v4.y, na[j]);
            na[j] = fmaf(p2, v4.z, na[j]);
            na[j] = fmaf(p3, v4.w, na[j]);
            da[j] += (p0 + p1) + (p2 + p3);
        }
    }

    #pragma unroll
    for (int j = 0; j < 8; ++j) {
        pn[h][i + j * 64] = na[j];   // stride-1 across lanes
        pd[h][i + j * 64] = da[j];
    }
    __syncthreads();

    // combine: thread tid finalizes query tid (all reads stride-1)
    float num = 0.f, den = 0.f;
    #pragma unroll
    for (int hh = 0; hh < 8; ++hh) {
        num += pn[hh][tid];
        den += pd[hh][tid];
    }
    att[(b * NN + tid) * DD + d] = num / den;   // 4B scattered, L2-absorbed
}

// ---------------------------------------------------------------------------
// K3: output projection. out[b,n,e] = att[b,n,:]·Wo[e,:] + bo[e]
// grid 512 x 512 thr = 4 waves/SIMD. lane = e, sub = tid>>7 owns 1 row.
// Wo^T loads per-lane coalesced dwordx4 (WTp slot 3); att rows uniform.
// ---------------------------------------------------------------------------
__global__ __launch_bounds__(512) void outproj_kernel(
    const float* __restrict__ att, const float* __restrict__ WTp,
    const float* __restrict__ bo, float* __restrict__ out)
{
    const int e   = threadIdx.x & (DD - 1);
    const int sub = threadIdx.x >> 7;
    const int g   = blockIdx.x * 4 + sub;

    const float4* wt4 = (const float4*)(WTp + (3 << 14));   // Wo slot
    const float4* xr  = (const float4*)(att + g * DD);

    float acc = 0.f;
    #pragma unroll 8
    for (int j4 = 0; j4 < DD / 4; ++j4) {
        const float4 w = wt4[j4 * DD + e];   // coalesced dwordx4
        const float4 a = xr[j4];             // wave-uniform broadcast
        acc = fmaf(a.x, w.x, fmaf(a.y, w.y, fmaf(a.z, w.z, fmaf(a.w, w.w, acc))));
    }

    out[g * DD + e] = acc + bo[e];           // coalesced
}

// ---------------------------------------------------------------------------
extern "C" void kernel_launch(void* const* d_in, const int* in_sizes, int n_in,
                              void* d_out, int out_size, void* d_ws, size_t ws_size,
                              hipStream_t stream)
{
    const float* q    = (const float*)d_in[0];
    const float* k    = (const float*)d_in[1];
    const float* v    = (const float*)d_in[2];
    const int*   mask = (const int*)  d_in[3];
    const float* Wq   = (const float*)d_in[4];
    const float* bq   = (const float*)d_in[5];
    const float* Wk   = (const float*)d_in[6];
    const float* bk   = (const float*)d_in[7];
    const float* Wv   = (const float*)d_in[8];
    const float* bv   = (const float*)d_in[9];
    const float* Wo   = (const float*)d_in[10];
    const float* bo   = (const float*)d_in[11];
    float* out = (float*)d_out;

    // ws layout (floats): qpT | kpT | vpT | att | WTp[4]  (~4.25 MB)
    float* ws  = (float*)d_ws;
    float* qpT = ws;                           // [B*D][N], masked+log2e-scaled
    float* kpT = ws + 1 * BB * DD * NN;        // [B*D][N]
    float* vpT = ws + 2 * BB * DD * NN;        // [B*D][N]
    float* att = ws + 3 * BB * DD * NN;        // [B*N][D]
    float* WTp = ws + 4 * BB * DD * NN;        // [4][32][128][4] packed weights

    wtrans_kernel<<<4 * DD * DD / 256, 256, 0, stream>>>(Wq, Wk, Wv, Wo, WTp);

    dim3 pgrid(BB * NN / 8, 3);
    proj_kernel<<<pgrid, 256, 0, stream>>>(q, k, v, WTp, bq, bk, bv, mask,
                                           qpT, kpT, vpT);

    attn_kernel<<<BB * DD, 512, 0, stream>>>(qpT, kpT, vpT, att);

    outproj_kernel<<<BB * NN / 4, 512, 0, stream>>>(att, WTp, bo, out);
}

// Round 8
// 120.873 us; speedup vs baseline: 1.1008x; 1.0432x over previous
//
#include <hip/hip_runtime.h>

// Problem constants (B=4, N=512, D=128, all f32)
#define BB 4
#define NN 512
#define DD 128

static constexpr float LOG2E = 1.4426950408889634f;
#define EXP2F(x) __builtin_amdgcn_exp2f(x)

// ---------------------------------------------------------------------------
// K1: input projections, per-block LDS-staged transposed weights.
// grid (128,3) x 256 thr; LDS 66 KB -> 2 blocks/CU. Block: matrix t, rows
// r0..r0+15 (one batch per block: 16 | 512). Stage W_t transposed+padded
// (pad 129 f4: scatter writes conflict-free, reads contiguous b128).
// Main loop: weight from LDS (no L2 latency), x rows wave-uniform s_load.
//   qpT[b*D+e][n] = mask ? (q·Wq[e]+bq[e]) * LOG2E : 0 ; kpT/vpT plain.
// Mask folded at q only (reference masks by query index n).
// ---------------------------------------------------------------------------
__global__ __launch_bounds__(256) void proj_kernel(
    const float* __restrict__ q, const float* __restrict__ k,
    const float* __restrict__ v, const int* __restrict__ mask,
    const float* __restrict__ Wq, const float* __restrict__ bq,
    const float* __restrict__ Wk, const float* __restrict__ bk,
    const float* __restrict__ Wv, const float* __restrict__ bv,
    float* __restrict__ qpT, float* __restrict__ kpT, float* __restrict__ vpT)
{
    __shared__ float4 sW[32 * 129];              // 66048 B

    const int tid = threadIdx.x;
    const int t   = blockIdx.y;                  // 0=q 1=k 2=v
    const float4* W4 = (const float4*)((t == 0) ? Wq : (t == 1) ? Wk : Wv);

    #pragma unroll
    for (int p = 0; p < 16; ++p) {
        const int f = p * 256 + tid;             // e = f>>5, c = f&31
        sW[(f & 31) * 129 + (f >> 5)] = W4[f];   // transpose stage, no conflicts
    }
    __syncthreads();

    const int e   = tid & 127;
    const int sub = tid >> 7;                    // 0/1, uniform per wave
    const int r0  = blockIdx.x * 16 + sub * 8;   // rows r0..r0+7
    const float* x    = (t == 0) ? q   : (t == 1) ? k   : v;
    const float* bias = (t == 0) ? bq  : (t == 1) ? bk  : bv;
    float*       outp = (t == 0) ? qpT : (t == 1) ? kpT : vpT;

    float acc[8] = {0.f, 0.f, 0.f, 0.f, 0.f, 0.f, 0.f, 0.f};
    #pragma unroll 4
    for (int j4 = 0; j4 < 32; ++j4) {
        const float4 w = sW[j4 * 129 + e];       // contiguous b128, conflict-free
        #pragma unroll
        for (int r = 0; r < 8; ++r) {            // wave-uniform -> s_load_dwordx4
            const float4 xr = ((const float4*)(x + (r0 + r) * DD))[j4];
            acc[r] = fmaf(xr.x, w.x, fmaf(xr.y, w.y,
                     fmaf(xr.z, w.z, fmaf(xr.w, w.w, acc[r]))));
        }
    }

    const float be = bias[e];
    const int b = r0 >> 9;                       // whole block is one batch
    #pragma unroll
    for (int r = 0; r < 8; ++r) {
        const int g = r0 + r;
        const int n = g & (NN - 1);
        float val = acc[r] + be;
        if (t == 0) val = (mask[g] != 0) ? val * LOG2E : 0.f;   // uniform branch
        outp[(b * DD + e) * NN + n] = val;
    }
}

// ---------------------------------------------------------------------------
// K2: per-channel softmax attention (R6-proven structure).
// grid 512 = (b,d) x 512 thr = 2 blocks/CU = 4 waves/SIMD.
// Thread (h = tid>>6, i = tid&63): keys [h*64, h*64+64) for 8 queries
// {i + j*64}. Each ds_read_b128 pair feeds 32 independent exps (ds-pipe
// ~2.6 us/CU vs 6.8 us exp floor). All LDS stride-1 conflict-free.
// No max-subtraction: scores bounded in exp2 domain; absmax 4.9e-4
// validated R1-R6.
// ---------------------------------------------------------------------------
__global__ __launch_bounds__(512) void attn_kernel(
    const float* __restrict__ qpT, const float* __restrict__ kpT,
    const float* __restrict__ vpT, float* __restrict__ att)
{
    __shared__ float sk[NN];
    __shared__ float sv[NN];
    __shared__ float pn[8][NN];
    __shared__ float pd[8][NN];

    const int bd  = blockIdx.x;      // 0..511
    const int b   = bd >> 7;
    const int d   = bd & (DD - 1);
    const int tid = threadIdx.x;
    const int h   = tid >> 6;        // key eighth, uniform per wave
    const int i   = tid & 63;

    sk[tid] = kpT[bd * NN + tid];    // coalesced
    sv[tid] = vpT[bd * NN + tid];

    float qv[8];
    #pragma unroll
    for (int j = 0; j < 8; ++j)
        qv[j] = qpT[bd * NN + i + j * 64];
    __syncthreads();

    const float4* kc = (const float4*)sk;
    const float4* vc = (const float4*)sv;

    float na[8], da[8];
    #pragma unroll
    for (int j = 0; j < 8; ++j) { na[j] = 0.f; da[j] = 0.f; }

    const int m4lo = h * 16;
    #pragma unroll 2
    for (int m4 = m4lo; m4 < m4lo + 16; ++m4) {
        const float4 k4 = kc[m4];    // broadcast, serves 8 queries
        const float4 v4 = vc[m4];
        #pragma unroll
        for (int j = 0; j < 8; ++j) {
            const float p0 = EXP2F(qv[j] * k4.x);
            const float p1 = EXP2F(qv[j] * k4.y);
            const float p2 = EXP2F(qv[j] * k4.z);
            const float p3 = EXP2F(qv[j] * k4.w);
            na[j] = fmaf(p0, v4.x, na[j]);
            na[j] = fmaf(p1, v4.y, na[j]);
            na[j] = fmaf(p2, v4.z, na[j]);
            na[j] = fmaf(p3, v4.w, na[j]);
            da[j] += (p0 + p1) + (p2 + p3);
        }
    }

    #pragma unroll
    for (int j = 0; j < 8; ++j) {
        pn[h][i + j * 64] = na[j];   // stride-1
        pd[h][i + j * 64] = da[j];
    }
    __syncthreads();

    float num = 0.f, den = 0.f;
    #pragma unroll
    for (int hh = 0; hh < 8; ++hh) {
        num += pn[hh][tid];
        den += pd[hh][tid];
    }
    att[(b * NN + tid) * DD + d] = num / den;   // 4B scatter, L2-absorbed
}

// ---------------------------------------------------------------------------
// K3: output projection, per-block LDS-staged Wo (same layout as K1).
// grid 512 x 256 thr = 2 blocks/CU; block handles rows g0..g0+3
// (sub = tid>>7 owns 2). att rows wave-uniform s_load (kernel boundary
// makes K2's writes visible). out writes lane-coalesced.
// ---------------------------------------------------------------------------
__global__ __launch_bounds__(256) void outproj_kernel(
    const float* __restrict__ att, const float* __restrict__ Wo,
    const float* __restrict__ bo, float* __restrict__ out)
{
    __shared__ float4 sW[32 * 129];              // 66048 B

    const int tid = threadIdx.x;
    const float4* Wo4 = (const float4*)Wo;
    #pragma unroll
    for (int p = 0; p < 16; ++p) {
        const int f = p * 256 + tid;
        sW[(f & 31) * 129 + (f >> 5)] = Wo4[f];
    }
    __syncthreads();

    const int e   = tid & 127;
    const int sub = tid >> 7;
    const int g0  = blockIdx.x * 4 + sub * 2;    // rows g0, g0+1

    const float4* x0 = (const float4*)(att + g0 * DD);
    const float4* x1 = (const float4*)(att + (g0 + 1) * DD);

    float a0 = 0.f, a1 = 0.f;
    #pragma unroll 4
    for (int j4 = 0; j4 < 32; ++j4) {
        const float4 w  = sW[j4 * 129 + e];      // conflict-free b128
        const float4 r0 = x0[j4];                // uniform -> s_load
        const float4 r1 = x1[j4];
        a0 = fmaf(r0.x, w.x, fmaf(r0.y, w.y, fmaf(r0.z, w.z, fmaf(r0.w, w.w, a0))));
        a1 = fmaf(r1.x, w.x, fmaf(r1.y, w.y, fmaf(r1.z, w.z, fmaf(r1.w, w.w, a1))));
    }

    const float boe = bo[e];
    out[(g0    ) * DD + e] = a0 + boe;           // coalesced
    out[(g0 + 1) * DD + e] = a1 + boe;
}

// ---------------------------------------------------------------------------
extern "C" void kernel_launch(void* const* d_in, const int* in_sizes, int n_in,
                              void* d_out, int out_size, void* d_ws, size_t ws_size,
                              hipStream_t stream)
{
    const float* q    = (const float*)d_in[0];
    const float* k    = (const float*)d_in[1];
    const float* v    = (const float*)d_in[2];
    const int*   mask = (const int*)  d_in[3];
    const float* Wq   = (const float*)d_in[4];
    const float* bq   = (const float*)d_in[5];
    const float* Wk   = (const float*)d_in[6];
    const float* bk   = (const float*)d_in[7];
    const float* Wv   = (const float*)d_in[8];
    const float* bv   = (const float*)d_in[9];
    const float* Wo   = (const float*)d_in[10];
    const float* bo   = (const float*)d_in[11];
    float* out = (float*)d_out;

    // ws layout (floats): qpT | kpT | vpT | att  (4 MB)
    float* ws  = (float*)d_ws;
    float* qpT = ws;                           // [B*D][N], masked+log2e-scaled
    float* kpT = ws + 1 * BB * DD * NN;        // [B*D][N]
    float* vpT = ws + 2 * BB * DD * NN;        // [B*D][N]
    float* att = ws + 3 * BB * DD * NN;        // [B*N][D]

    dim3 pgrid(BB * NN / 16, 3);
    proj_kernel<<<pgrid, 256, 0, stream>>>(q, k, v, mask, Wq, bq, Wk, bk,
                                           Wv, bv, qpT, kpT, vpT);

    attn_kernel<<<BB * DD, 512, 0, stream>>>(qpT, kpT, vpT, att);

    outproj_kernel<<<BB * NN / 4, 256, 0, stream>>>(att, Wo, bo, out);
}

// Round 9
// 120.212 us; speedup vs baseline: 1.1068x; 1.0055x over previous
//
#include <hip/hip_runtime.h>

// Problem constants (B=4, N=512, D=128, all f32)
#define BB 4
#define NN 512
#define DD 128

static constexpr float LOG2E = 1.4426950408889634f;
#define EXP2F(x) __builtin_amdgcn_exp2f(x)

typedef float v2f __attribute__((ext_vector_type(2)));   // -> v_pk_*_f32

// ---------------------------------------------------------------------------
// K1: input projections, per-block LDS-staged transposed weights.
// grid (128,3) x 256 thr; LDS 66 KB -> 2 blocks/CU. Block: matrix t, rows
// r0..r0+15 (one batch per block). Weights transposed+padded in LDS
// (pad 129 f4: reads contiguous b128, conflict-free). x rows wave-uniform
// s_load. Stores packed as 2x global_store_dwordx4 per thread (8 n-
// consecutive floats per lane) instead of 8 scalar stores.
//   qpT[b*D+e][n] = mask ? (q·Wq[e]+bq[e]) * LOG2E : 0 ; kpT/vpT plain.
// ---------------------------------------------------------------------------
__global__ __launch_bounds__(256) void proj_kernel(
    const float* __restrict__ q, const float* __restrict__ k,
    const float* __restrict__ v, const int* __restrict__ mask,
    const float* __restrict__ Wq, const float* __restrict__ bq,
    const float* __restrict__ Wk, const float* __restrict__ bk,
    const float* __restrict__ Wv, const float* __restrict__ bv,
    float* __restrict__ qpT, float* __restrict__ kpT, float* __restrict__ vpT)
{
    __shared__ float4 sW[32 * 129];              // 66048 B

    const int tid = threadIdx.x;
    const int t   = blockIdx.y;                  // 0=q 1=k 2=v
    const float4* W4 = (const float4*)((t == 0) ? Wq : (t == 1) ? Wk : Wv);

    #pragma unroll
    for (int p = 0; p < 16; ++p) {
        const int f = p * 256 + tid;             // e = f>>5, c = f&31
        sW[(f & 31) * 129 + (f >> 5)] = W4[f];
    }
    __syncthreads();

    const int e   = tid & 127;
    const int sub = tid >> 7;                    // 0/1, uniform per wave
    const int r0  = blockIdx.x * 16 + sub * 8;   // rows r0..r0+7
    const float* x    = (t == 0) ? q   : (t == 1) ? k   : v;
    const float* bias = (t == 0) ? bq  : (t == 1) ? bk  : bv;
    float*       outp = (t == 0) ? qpT : (t == 1) ? kpT : vpT;

    float acc[8] = {0.f, 0.f, 0.f, 0.f, 0.f, 0.f, 0.f, 0.f};
    #pragma unroll 4
    for (int j4 = 0; j4 < 32; ++j4) {
        const float4 w = sW[j4 * 129 + e];       // contiguous b128
        #pragma unroll
        for (int r = 0; r < 8; ++r) {            // wave-uniform -> s_load_dwordx4
            const float4 xr = ((const float4*)(x + (r0 + r) * DD))[j4];
            acc[r] = fmaf(xr.x, w.x, fmaf(xr.y, w.y,
                     fmaf(xr.z, w.z, fmaf(xr.w, w.w, acc[r]))));
        }
    }

    const float be = bias[e];
    const int b = r0 >> 9;
    const int n0 = r0 & (NN - 1);
    float o[8];
    #pragma unroll
    for (int r = 0; r < 8; ++r) {
        float val = acc[r] + be;
        if (t == 0) val = (mask[r0 + r] != 0) ? val * LOG2E : 0.f;  // uniform
        o[r] = val;
    }
    float4* dst = (float4*)(outp + (b * DD + e) * NN + n0);
    dst[0] = make_float4(o[0], o[1], o[2], o[3]);    // 2x dwordx4 per lane
    dst[1] = make_float4(o[4], o[5], o[6], o[7]);
}

// ---------------------------------------------------------------------------
// K2: per-channel softmax attention, packed-fp32 math, transposed output.
// grid 512 = (b,d) x 512 thr = 2 blocks/CU = 4 waves/SIMD.
// Thread (h = tid>>6, i = tid&63): keys [h*64, +64) for 8 queries {i+j*64}.
// Non-exp math on v2f -> v_pk_mul/v_pk_fma/v_pk_add (issue slots per
// 4 elems/query: 15 -> 10; exp pipe is the 6.8 us floor).
// Output written TRANSPOSED attT[bd][n] -> fully coalesced stores (old
// [n][d] layout cost 64 partial lines per wave-store, cross-XCD shared).
// No max-subtraction: scores bounded in exp2 domain; absmax 4.9e-4 R1-R8.
// ---------------------------------------------------------------------------
__global__ __launch_bounds__(512) void attn_kernel(
    const float* __restrict__ qpT, const float* __restrict__ kpT,
    const float* __restrict__ vpT, float* __restrict__ attT)
{
    __shared__ float sk[NN];
    __shared__ float sv[NN];
    __shared__ float pn[8][NN];
    __shared__ float pd[8][NN];

    const int bd  = blockIdx.x;      // 0..511
    const int tid = threadIdx.x;
    const int h   = tid >> 6;        // key eighth, uniform per wave
    const int i   = tid & 63;

    sk[tid] = kpT[bd * NN + tid];    // coalesced
    sv[tid] = vpT[bd * NN + tid];

    v2f qv2[8];
    #pragma unroll
    for (int j = 0; j < 8; ++j) {
        const float qv = qpT[bd * NN + i + j * 64];
        qv2[j] = (v2f){qv, qv};
    }
    __syncthreads();

    const float4* kc = (const float4*)sk;
    const float4* vc = (const float4*)sv;

    v2f na[8], da[8];
    #pragma unroll
    for (int j = 0; j < 8; ++j) { na[j] = (v2f){0.f, 0.f}; da[j] = (v2f){0.f, 0.f}; }

    const int m4lo = h * 16;
    #pragma unroll 2
    for (int m4 = m4lo; m4 < m4lo + 16; ++m4) {
        const float4 k4 = kc[m4];    // broadcast b128, serves 8 queries
        const float4 v4 = vc[m4];
        const v2f kxy = (v2f){k4.x, k4.y}, kzw = (v2f){k4.z, k4.w};
        const v2f vxy = (v2f){v4.x, v4.y}, vzw = (v2f){v4.z, v4.w};
        #pragma unroll
        for (int j = 0; j < 8; ++j) {
            const v2f a01 = qv2[j] * kxy;        // v_pk_mul_f32
            const v2f a23 = qv2[j] * kzw;
            const v2f p01 = (v2f){EXP2F(a01.x), EXP2F(a01.y)};
            const v2f p23 = (v2f){EXP2F(a23.x), EXP2F(a23.y)};
            na[j] = na[j] + p01 * vxy;           // v_pk_fma_f32 (contract)
            na[j] = na[j] + p23 * vzw;
            da[j] = da[j] + (p01 + p23);         // v_pk_add_f32 x2
        }
    }

    #pragma unroll
    for (int j = 0; j < 8; ++j) {
        pn[h][i + j * 64] = na[j].x + na[j].y;   // stride-1
        pd[h][i + j * 64] = da[j].x + da[j].y;
    }
    __syncthreads();

    float num = 0.f, den = 0.f;
    #pragma unroll
    for (int hh = 0; hh < 8; ++hh) {
        num += pn[hh][tid];
        den += pd[hh][tid];
    }
    attT[bd * NN + tid] = num / den;             // fully coalesced
}

// ---------------------------------------------------------------------------
// K3: output projection from transposed att.
//   out[b,n,e] = sum_d attT[b*128+d][n] * Wo[e][d] + bo[e]
// grid 512 x 256 thr; Wo LDS-staged transposed (reads b128 conflict-free);
// att gather is wave-uniform scalar loads (4 per j4, stride 2 KB — SMEM
// pipelined). out stores lane-coalesced.
// ---------------------------------------------------------------------------
__global__ __launch_bounds__(256) void outproj_kernel(
    const float* __restrict__ attT, const float* __restrict__ Wo,
    const float* __restrict__ bo, float* __restrict__ out)
{
    __shared__ float4 sW[32 * 129];              // 66048 B

    const int tid = threadIdx.x;
    const float4* Wo4 = (const float4*)Wo;
    #pragma unroll
    for (int p = 0; p < 16; ++p) {
        const int f = p * 256 + tid;
        sW[(f & 31) * 129 + (f >> 5)] = Wo4[f];
    }
    __syncthreads();

    const int e   = tid & 127;
    const int sub = tid >> 7;
    const int g0  = blockIdx.x * 4 + sub * 2;    // rows g0, g0+1
    const int b   = g0 >> 9;
    const int n0  = g0 & (NN - 1);
    const float* ac = attT + (b * DD) * NN;      // attT[b*128+d][n]

    float a0 = 0.f, a1 = 0.f;
    #pragma unroll 4
    for (int j4 = 0; j4 < 32; ++j4) {
        const float4 w = sW[j4 * 129 + e];       // conflict-free b128
        #pragma unroll
        for (int c = 0; c < 4; ++c) {
            const int d = j4 * 4 + c;
            const float x0 = ac[d * NN + n0];        // uniform s_load
            const float x1 = ac[d * NN + n0 + 1];
            const float wc = (c == 0) ? w.x : (c == 1) ? w.y : (c == 2) ? w.z : w.w;
            a0 = fmaf(x0, wc, a0);
            a1 = fmaf(x1, wc, a1);
        }
    }

    const float boe = bo[e];
    out[(g0    ) * DD + e] = a0 + boe;           // coalesced
    out[(g0 + 1) * DD + e] = a1 + boe;
}

// ---------------------------------------------------------------------------
extern "C" void kernel_launch(void* const* d_in, const int* in_sizes, int n_in,
                              void* d_out, int out_size, void* d_ws, size_t ws_size,
                              hipStream_t stream)
{
    const float* q    = (const float*)d_in[0];
    const float* k    = (const float*)d_in[1];
    const float* v    = (const float*)d_in[2];
    const int*   mask = (const int*)  d_in[3];
    const float* Wq   = (const float*)d_in[4];
    const float* bq   = (const float*)d_in[5];
    const float* Wk   = (const float*)d_in[6];
    const float* bk   = (const float*)d_in[7];
    const float* Wv   = (const float*)d_in[8];
    const float* bv   = (const float*)d_in[9];
    const float* Wo   = (const float*)d_in[10];
    const float* bo   = (const float*)d_in[11];
    float* out = (float*)d_out;

    // ws layout (floats): qpT | kpT | vpT | attT  (4 MB)
    float* ws   = (float*)d_ws;
    float* qpT  = ws;                          // [B*D][N], masked+log2e-scaled
    float* kpT  = ws + 1 * BB * DD * NN;       // [B*D][N]
    float* vpT  = ws + 2 * BB * DD * NN;       // [B*D][N]
    float* attT = ws + 3 * BB * DD * NN;       // [B*D][N] transposed

    dim3 pgrid(BB * NN / 16, 3);
    proj_kernel<<<pgrid, 256, 0, stream>>>(q, k, v, mask, Wq, bq, Wk, bk,
                                           Wv, bv, qpT, kpT, vpT);

    attn_kernel<<<BB * DD, 512, 0, stream>>>(qpT, kpT, vpT, attT);

    outproj_kernel<<<BB * NN / 4, 256, 0, stream>>>(attT, Wo, bo, out);
}

// Round 10
// 111.816 us; speedup vs baseline: 1.1899x; 1.0751x over previous
//
#include <hip/hip_runtime.h>

// Problem constants (B=4, N=512, D=128, all f32)
#define BB 4
#define NN 512
#define DD 128

static constexpr float LOG2E = 1.4426950408889634f;
#define EXP2F(x) __builtin_amdgcn_exp2f(x)

// ---------------------------------------------------------------------------
// K1: input projections, weights LDS-staged in TWO 33 KB halves so 3-4
// blocks/CU fit (vs 2 at 66 KB). grid (256,3) x 256 thr = 768 blocks =
// 3 blocks/CU = 3 waves/SIMD (vs R9's 1.5). Block: matrix t, rows
// r0..r0+7 (one batch per block, 8 | 512); thread: channel e = tid&127,
// sub = tid>>7 picks 4 rows. Weight reads contiguous b128 conflict-free;
// x rows wave-uniform s_load (readfirstlane-pinned sub).
//   qpT[b*D+e][n] = mask ? (q·Wq[e]+bq[e]) * LOG2E : 0 ; kpT/vpT plain.
// ---------------------------------------------------------------------------
__global__ __launch_bounds__(256) void proj_kernel(
    const float* __restrict__ q, const float* __restrict__ k,
    const float* __restrict__ v, const int* __restrict__ mask,
    const float* __restrict__ Wq, const float* __restrict__ bq,
    const float* __restrict__ Wk, const float* __restrict__ bk,
    const float* __restrict__ Wv, const float* __restrict__ bv,
    float* __restrict__ qpT, float* __restrict__ kpT, float* __restrict__ vpT)
{
    __shared__ float4 sW[16 * 129];              // 33024 B

    const int tid = threadIdx.x;
    const int t   = blockIdx.y;                  // 0=q 1=k 2=v
    const float4* W4 = (const float4*)((t == 0) ? Wq : (t == 1) ? Wk : Wv);

    const int e   = tid & 127;
    const int sub = __builtin_amdgcn_readfirstlane(tid >> 7);   // 0/1
    const int r0  = blockIdx.x * 8 + sub * 4;    // rows r0..r0+3
    const float* x    = (t == 0) ? q   : (t == 1) ? k   : v;
    const float* bias = (t == 0) ? bq  : (t == 1) ? bk  : bv;
    float*       outp = (t == 0) ? qpT : (t == 1) ? kpT : vpT;

    float acc[4] = {0.f, 0.f, 0.f, 0.f};

    #pragma unroll
    for (int half = 0; half < 2; ++half) {
        // stage 16 j4-columns of W (transposed): sW[c][e] = W[e][half*16+c]
        #pragma unroll
        for (int p = 0; p < 8; ++p) {
            const int f = p * 256 + tid;         // e' = f>>4, c = f&15
            sW[(f & 15) * 129 + (f >> 4)] = W4[(f >> 4) * 32 + half * 16 + (f & 15)];
        }
        __syncthreads();

        #pragma unroll 4
        for (int c = 0; c < 16; ++c) {
            const int j4 = half * 16 + c;
            const float4 w = sW[c * 129 + e];    // contiguous b128
            #pragma unroll
            for (int r = 0; r < 4; ++r) {        // wave-uniform -> s_load_dwordx4
                const float4 xr = ((const float4*)(x + (r0 + r) * DD))[j4];
                acc[r] = fmaf(xr.x, w.x, fmaf(xr.y, w.y,
                         fmaf(xr.z, w.z, fmaf(xr.w, w.w, acc[r]))));
            }
        }
        __syncthreads();                         // before restaging
    }

    const float be = bias[e];
    const int b  = r0 >> 9;
    const int n0 = r0 & (NN - 1);
    float o[4];
    #pragma unroll
    for (int r = 0; r < 4; ++r) {
        float val = acc[r] + be;
        if (t == 0) val = (mask[r0 + r] != 0) ? val * LOG2E : 0.f;  // uniform
        o[r] = val;
    }
    *(float4*)(outp + (b * DD + e) * NN + n0) = make_float4(o[0], o[1], o[2], o[3]);
}

// ---------------------------------------------------------------------------
// K2: per-channel softmax attention, query-halved for max occupancy.
// grid (512 bd, 2 qhalf) x 512 thr = 8192 waves = 8 waves/SIMD (cap).
// LDS 20 KB -> 4 blocks/CU fits; __launch_bounds__(512,8) caps VGPR at 64
// (lean scalar loop ~40). Thread (h = tid>>6 key-eighth, i = tid&63):
// 4 queries {qhalf*256 + i + j*64} x 64 keys. Each broadcast ds_read_b128
// pair serves 4 queries (LDS pipe ~5.1 us/CU < 6.8 us exp floor).
// No max-subtraction: scores bounded in exp2 domain; absmax 4.9e-4 R1-R9.
// ---------------------------------------------------------------------------
__global__ __launch_bounds__(512, 8) void attn_kernel(
    const float* __restrict__ qpT, const float* __restrict__ kpT,
    const float* __restrict__ vpT, float* __restrict__ attT)
{
    __shared__ float sk[NN];
    __shared__ float sv[NN];
    __shared__ float pn[8][256];
    __shared__ float pd[8][256];

    const int bd  = blockIdx.x;          // 0..511
    const int qh  = blockIdx.y;          // query half
    const int tid = threadIdx.x;
    const int h   = tid >> 6;            // key eighth, uniform per wave
    const int i   = tid & 63;

    sk[tid] = kpT[bd * NN + tid];        // coalesced
    sv[tid] = vpT[bd * NN + tid];

    float qv[4];
    #pragma unroll
    for (int j = 0; j < 4; ++j)
        qv[j] = qpT[bd * NN + qh * 256 + i + j * 64];
    __syncthreads();

    const float4* kc = (const float4*)sk;
    const float4* vc = (const float4*)sv;

    float na[4] = {0.f, 0.f, 0.f, 0.f};
    float da[4] = {0.f, 0.f, 0.f, 0.f};

    const int m4lo = h * 16;
    #pragma unroll 2
    for (int m4 = m4lo; m4 < m4lo + 16; ++m4) {
        const float4 k4 = kc[m4];        // broadcast, serves 4 queries
        const float4 v4 = vc[m4];
        #pragma unroll
        for (int j = 0; j < 4; ++j) {
            const float p0 = EXP2F(qv[j] * k4.x);
            const float p1 = EXP2F(qv[j] * k4.y);
            const float p2 = EXP2F(qv[j] * k4.z);
            const float p3 = EXP2F(qv[j] * k4.w);
            na[j] = fmaf(p0, v4.x, na[j]);
            na[j] = fmaf(p1, v4.y, na[j]);
            na[j] = fmaf(p2, v4.z, na[j]);
            na[j] = fmaf(p3, v4.w, na[j]);
            da[j] += (p0 + p1) + (p2 + p3);
        }
    }

    #pragma unroll
    for (int j = 0; j < 4; ++j) {
        pn[h][i + j * 64] = na[j];       // stride-1
        pd[h][i + j * 64] = da[j];
    }
    __syncthreads();

    if (tid < 256) {                     // combine 8 key-eighths
        float num = 0.f, den = 0.f;
        #pragma unroll
        for (int hh = 0; hh < 8; ++hh) {
            num += pn[hh][tid];
            den += pd[hh][tid];
        }
        attT[bd * NN + qh * 256 + tid] = num / den;   // coalesced
    }
}

// ---------------------------------------------------------------------------
// K3: output projection from transposed att, Wo LDS-staged in two 33 KB
// halves. grid 1024 x 256 thr = 4 blocks/CU = 4 waves/SIMD (vs R9's 2).
// Block: rows g0..g0+1 (sub picks one). att gather wave-uniform s_load;
// Wo reads contiguous b128; out stores lane-coalesced.
//   out[b,n,e] = sum_d attT[b*128+d][n] * Wo[e][d] + bo[e]
// ---------------------------------------------------------------------------
__global__ __launch_bounds__(256) void outproj_kernel(
    const float* __restrict__ attT, const float* __restrict__ Wo,
    const float* __restrict__ bo, float* __restrict__ out)
{
    __shared__ float4 sW[16 * 129];              // 33024 B

    const int tid = threadIdx.x;
    const float4* Wo4 = (const float4*)Wo;

    const int e   = tid & 127;
    const int sub = __builtin_amdgcn_readfirstlane(tid >> 7);
    const int g   = blockIdx.x * 2 + sub;        // one row per thread
    const int b   = g >> 9;
    const int n   = g & (NN - 1);
    const float* ac = attT + (b * DD) * NN;

    float acc = 0.f;
    #pragma unroll
    for (int half = 0; half < 2; ++half) {
        #pragma unroll
        for (int p = 0; p < 8; ++p) {
            const int f = p * 256 + tid;
            sW[(f & 15) * 129 + (f >> 4)] = Wo4[(f >> 4) * 32 + half * 16 + (f & 15)];
        }
        __syncthreads();

        #pragma unroll 4
        for (int c = 0; c < 16; ++c) {
            const int j4 = half * 16 + c;
            const float4 w = sW[c * 129 + e];    // contiguous b128
            #pragma unroll
            for (int cc = 0; cc < 4; ++cc) {
                const int d = j4 * 4 + cc;
                const float xv = ac[d * NN + n]; // uniform s_load
                const float wc = (cc == 0) ? w.x : (cc == 1) ? w.y
                               : (cc == 2) ? w.z : w.w;
                acc = fmaf(xv, wc, acc);
            }
        }
        __syncthreads();
    }

    out[g * DD + e] = acc + bo[e];               // coalesced
}

// ---------------------------------------------------------------------------
extern "C" void kernel_launch(void* const* d_in, const int* in_sizes, int n_in,
                              void* d_out, int out_size, void* d_ws, size_t ws_size,
                              hipStream_t stream)
{
    const float* q    = (const float*)d_in[0];
    const float* k    = (const float*)d_in[1];
    const float* v    = (const float*)d_in[2];
    const int*   mask = (const int*)  d_in[3];
    const float* Wq   = (const float*)d_in[4];
    const float* bq   = (const float*)d_in[5];
    const float* Wk   = (const float*)d_in[6];
    const float* bk   = (const float*)d_in[7];
    const float* Wv   = (const float*)d_in[8];
    const float* bv   = (const float*)d_in[9];
    const float* Wo   = (const float*)d_in[10];
    const float* bo   = (const float*)d_in[11];
    float* out = (float*)d_out;

    // ws layout (floats): qpT | kpT | vpT | attT  (4 MB)
    float* ws   = (float*)d_ws;
    float* qpT  = ws;                          // [B*D][N], masked+log2e-scaled
    float* kpT  = ws + 1 * BB * DD * NN;       // [B*D][N]
    float* vpT  = ws + 2 * BB * DD * NN;       // [B*D][N]
    float* attT = ws + 3 * BB * DD * NN;       // [B*D][N] transposed

    dim3 pgrid(BB * NN / 8, 3);
    proj_kernel<<<pgrid, 256, 0, stream>>>(q, k, v, mask, Wq, bq, Wk, bk,
                                           Wv, bv, qpT, kpT, vpT);

    dim3 agrid(BB * DD, 2);
    attn_kernel<<<agrid, 512, 0, stream>>>(qpT, kpT, vpT, attT);

    outproj_kernel<<<BB * NN / 2, 256, 0, stream>>>(attT, Wo, bo, out);
}

// Round 11
// 107.589 us; speedup vs baseline: 1.2367x; 1.0393x over previous
//
#include <hip/hip_runtime.h>

// Problem constants (B=4, N=512, D=128, all f32)
#define BB 4
#define NN 512
#define DD 128

static constexpr float LOG2E = 1.4426950408889634f;
#define EXP2F(x) __builtin_amdgcn_exp2f(x)

typedef float v2f __attribute__((ext_vector_type(2)));   // -> v_pk_*_f32

// ---------------------------------------------------------------------------
// K1: input projections, packed-fp32 FMA, two-half LDS weight staging.
// grid (256,3) x 256 thr = 768 blocks = 3 blocks/CU = 3 waves/SIMD.
// Block: matrix t, rows r0..r0+7; thread: channel e = tid&127, sub picks
// 4 rows. Weights transposed in LDS (reads contiguous b128, conflict-free);
// x rows wave-uniform s_load. Inner product packed over j-pairs:
// 2 v_pk_fma per (row, j4) instead of 4 v_fma — proj was VALU-bound at
// 5.1 us/CU, packed halves it.
//   qpT[b*D+e][n] = mask ? (q·Wq[e]+bq[e]) * LOG2E : 0 ; kpT/vpT plain.
// ---------------------------------------------------------------------------
__global__ __launch_bounds__(256) void proj_kernel(
    const float* __restrict__ q, const float* __restrict__ k,
    const float* __restrict__ v, const int* __restrict__ mask,
    const float* __restrict__ Wq, const float* __restrict__ bq,
    const float* __restrict__ Wk, const float* __restrict__ bk,
    const float* __restrict__ Wv, const float* __restrict__ bv,
    float* __restrict__ qpT, float* __restrict__ kpT, float* __restrict__ vpT)
{
    __shared__ float4 sW[16 * 129];              // 33024 B

    const int tid = threadIdx.x;
    const int t   = blockIdx.y;                  // 0=q 1=k 2=v
    const float4* W4 = (const float4*)((t == 0) ? Wq : (t == 1) ? Wk : Wv);

    const int e   = tid & 127;
    const int sub = __builtin_amdgcn_readfirstlane(tid >> 7);   // 0/1
    const int r0  = blockIdx.x * 8 + sub * 4;    // rows r0..r0+3
    const float* x    = (t == 0) ? q   : (t == 1) ? k   : v;
    const float* bias = (t == 0) ? bq  : (t == 1) ? bk  : bv;
    float*       outp = (t == 0) ? qpT : (t == 1) ? kpT : vpT;

    v2f acc[4];
    #pragma unroll
    for (int r = 0; r < 4; ++r) acc[r] = (v2f){0.f, 0.f};

    #pragma unroll
    for (int half = 0; half < 2; ++half) {
        // stage 16 j4-columns of W (transposed): sW[c][e'] = W[e'][half*16+c]
        #pragma unroll
        for (int p = 0; p < 8; ++p) {
            const int f = p * 256 + tid;         // e' = f>>4, c = f&15
            sW[(f & 15) * 129 + (f >> 4)] = W4[(f >> 4) * 32 + half * 16 + (f & 15)];
        }
        __syncthreads();

        #pragma unroll 4
        for (int c = 0; c < 16; ++c) {
            const int j4 = half * 16 + c;
            const float4 w = sW[c * 129 + e];    // contiguous b128
            const v2f wxy = (v2f){w.x, w.y}, wzw = (v2f){w.z, w.w};
            #pragma unroll
            for (int r = 0; r < 4; ++r) {        // wave-uniform -> s_load_dwordx4
                const float4 xr = ((const float4*)(x + (r0 + r) * DD))[j4];
                acc[r] += (v2f){xr.x, xr.y} * wxy;   // v_pk_fma_f32
                acc[r] += (v2f){xr.z, xr.w} * wzw;
            }
        }
        __syncthreads();                         // before restaging
    }

    const float be = bias[e];
    const int b  = r0 >> 9;
    const int n0 = r0 & (NN - 1);
    float o[4];
    #pragma unroll
    for (int r = 0; r < 4; ++r) {
        float val = (acc[r].x + acc[r].y) + be;
        if (t == 0) val = (mask[r0 + r] != 0) ? val * LOG2E : 0.f;  // uniform
        o[r] = val;
    }
    *(float4*)(outp + (b * DD + e) * NN + n0) = make_float4(o[0], o[1], o[2], o[3]);
}

// ---------------------------------------------------------------------------
// K2: per-channel softmax attention, query-halved, packed non-exp math.
// grid (512 bd, 2 qhalf) x 512 thr = 8192 waves = 8 waves/SIMD (cap);
// LDS 20 KB -> 4 blocks/CU. Thread (h = key-eighth, i = tid&63): 4 queries
// x 64 keys; each broadcast ds_read_b128 pair serves 4 queries.
// Non-exp math on v2f (v_pk_mul/pk_fma/pk_add): VALU slots per 4 elems
// 11 -> 5.5, freeing issue bandwidth for the quarter-rate exp pipe
// (the 6.8 us floor). VGPR ~48 < 64, occupancy preserved.
// No max-subtraction: scores bounded in exp2 domain; absmax 4.9e-4 R1-R10.
// ---------------------------------------------------------------------------
__global__ __launch_bounds__(512, 8) void attn_kernel(
    const float* __restrict__ qpT, const float* __restrict__ kpT,
    const float* __restrict__ vpT, float* __restrict__ attT)
{
    __shared__ float sk[NN];
    __shared__ float sv[NN];
    __shared__ float pn[8][256];
    __shared__ float pd[8][256];

    const int bd  = blockIdx.x;          // 0..511
    const int qh  = blockIdx.y;          // query half
    const int tid = threadIdx.x;
    const int h   = tid >> 6;            // key eighth, uniform per wave
    const int i   = tid & 63;

    sk[tid] = kpT[bd * NN + tid];        // coalesced
    sv[tid] = vpT[bd * NN + tid];

    v2f qv2[4];
    #pragma unroll
    for (int j = 0; j < 4; ++j) {
        const float qv = qpT[bd * NN + qh * 256 + i + j * 64];
        qv2[j] = (v2f){qv, qv};
    }
    __syncthreads();

    const float4* kc = (const float4*)sk;
    const float4* vc = (const float4*)sv;

    v2f na[4], da[4];
    #pragma unroll
    for (int j = 0; j < 4; ++j) { na[j] = (v2f){0.f, 0.f}; da[j] = (v2f){0.f, 0.f}; }

    const int m4lo = h * 16;
    #pragma unroll 2
    for (int m4 = m4lo; m4 < m4lo + 16; ++m4) {
        const float4 k4 = kc[m4];        // broadcast, serves 4 queries
        const float4 v4 = vc[m4];
        const v2f kxy = (v2f){k4.x, k4.y}, kzw = (v2f){k4.z, k4.w};
        const v2f vxy = (v2f){v4.x, v4.y}, vzw = (v2f){v4.z, v4.w};
        #pragma unroll
        for (int j = 0; j < 4; ++j) {
            const v2f a01 = qv2[j] * kxy;            // v_pk_mul_f32
            const v2f a23 = qv2[j] * kzw;
            const v2f p01 = (v2f){EXP2F(a01.x), EXP2F(a01.y)};
            const v2f p23 = (v2f){EXP2F(a23.x), EXP2F(a23.y)};
            na[j] += p01 * vxy;                      // v_pk_fma_f32
            na[j] += p23 * vzw;
            da[j] += p01 + p23;                      // v_pk_add_f32
        }
    }

    #pragma unroll
    for (int j = 0; j < 4; ++j) {
        pn[h][i + j * 64] = na[j].x + na[j].y;       // stride-1
        pd[h][i + j * 64] = da[j].x + da[j].y;
    }
    __syncthreads();

    if (tid < 256) {                     // combine 8 key-eighths
        float num = 0.f, den = 0.f;
        #pragma unroll
        for (int hh = 0; hh < 8; ++hh) {
            num += pn[hh][tid];
            den += pd[hh][tid];
        }
        attT[bd * NN + qh * 256 + tid] = num / den;  // coalesced
    }
}

// ---------------------------------------------------------------------------
// K3: output projection from transposed att, packed FMA, two-half Wo stage.
// grid 1024 x 256 thr = 4 blocks/CU = 4 waves/SIMD. Block: rows g0..g0+1
// (sub picks one). att gather wave-uniform s_load (packed into v2f pairs);
// Wo reads contiguous b128; out stores lane-coalesced.
//   out[b,n,e] = sum_d attT[b*128+d][n] * Wo[e][d] + bo[e]
// ---------------------------------------------------------------------------
__global__ __launch_bounds__(256) void outproj_kernel(
    const float* __restrict__ attT, const float* __restrict__ Wo,
    const float* __restrict__ bo, float* __restrict__ out)
{
    __shared__ float4 sW[16 * 129];              // 33024 B

    const int tid = threadIdx.x;
    const float4* Wo4 = (const float4*)Wo;

    const int e   = tid & 127;
    const int sub = __builtin_amdgcn_readfirstlane(tid >> 7);
    const int g   = blockIdx.x * 2 + sub;        // one row per thread
    const int b   = g >> 9;
    const int n   = g & (NN - 1);
    const float* ac = attT + (b * DD) * NN;

    v2f acc = (v2f){0.f, 0.f};
    #pragma unroll
    for (int half = 0; half < 2; ++half) {
        #pragma unroll
        for (int p = 0; p < 8; ++p) {
            const int f = p * 256 + tid;
            sW[(f & 15) * 129 + (f >> 4)] = Wo4[(f >> 4) * 32 + half * 16 + (f & 15)];
        }
        __syncthreads();

        #pragma unroll 4
        for (int c = 0; c < 16; ++c) {
            const int j4 = half * 16 + c;
            const float4 w = sW[c * 129 + e];    // contiguous b128
            const int d = j4 * 4;
            const float x0 = ac[(d    ) * NN + n];   // uniform s_load x4
            const float x1 = ac[(d + 1) * NN + n];
            const float x2 = ac[(d + 2) * NN + n];
            const float x3 = ac[(d + 3) * NN + n];
            acc += (v2f){x0, x1} * (v2f){w.x, w.y};  // v_pk_fma_f32
            acc += (v2f){x2, x3} * (v2f){w.z, w.w};
        }
        __syncthreads();
    }

    out[g * DD + e] = (acc.x + acc.y) + bo[e];   // coalesced
}

// ---------------------------------------------------------------------------
extern "C" void kernel_launch(void* const* d_in, const int* in_sizes, int n_in,
                              void* d_out, int out_size, void* d_ws, size_t ws_size,
                              hipStream_t stream)
{
    const float* q    = (const float*)d_in[0];
    const float* k    = (const float*)d_in[1];
    const float* v    = (const float*)d_in[2];
    const int*   mask = (const int*)  d_in[3];
    const float* Wq   = (const float*)d_in[4];
    const float* bq   = (const float*)d_in[5];
    const float* Wk   = (const float*)d_in[6];
    const float* bk   = (const float*)d_in[7];
    const float* Wv   = (const float*)d_in[8];
    const float* bv   = (const float*)d_in[9];
    const float* Wo   = (const float*)d_in[10];
    const float* bo   = (const float*)d_in[11];
    float* out = (float*)d_out;

    // ws layout (floats): qpT | kpT | vpT | attT  (4 MB)
    float* ws   = (float*)d_ws;
    float* qpT  = ws;                          // [B*D][N], masked+log2e-scaled
    float* kpT  = ws + 1 * BB * DD * NN;       // [B*D][N]
    float* vpT  = ws + 2 * BB * DD * NN;       // [B*D][N]
    float* attT = ws + 3 * BB * DD * NN;       // [B*D][N] transposed

    dim3 pgrid(BB * NN / 8, 3);
    proj_kernel<<<pgrid, 256, 0, stream>>>(q, k, v, mask, Wq, bq, Wk, bk,
                                           Wv, bv, qpT, kpT, vpT);

    dim3 agrid(BB * DD, 2);
    attn_kernel<<<agrid, 512, 0, stream>>>(qpT, kpT, vpT, attT);

    outproj_kernel<<<BB * NN / 2, 256, 0, stream>>>(attT, Wo, bo, out);
}